// Round 4
// baseline (315.554 us; speedup 1.0000x reference)
//
#include <hip/hip_runtime.h>
#include <math.h>

#define HH   768
#define WW   1024
#define CC   128
#define HWN  (HH*WW)          // 786432
#define KTOP 5000
#define CAND_CAP 204800
#define SEL_CAP  8192
#define NBINS    4096
#define BIN_BASE 0x3E800u     // __float_as_uint(0.25f) >> 12

// ---- workspace layout (bytes) ----
#define OFF_REP    0ull
#define OFF_SMAP   3145728ull
#define OFF_CAND   6291456ull
#define OFF_HIST   (OFF_CAND + (unsigned long long)CAND_CAP*8ull)
#define OFF_CTR    (OFF_HIST + (unsigned long long)NBINS*4ull)
#define OFF_SEL    (OFF_CTR + 64ull)
#define OFF_SORTED (OFF_SEL + (unsigned long long)SEL_CAP*8ull)
#define OFF_PART   (16ull*1024*1024)          // 4 SoA f32 planes, 3145728 B each
#define PART_PLANE 3145728ull

// correctly-rounded f32 exp via f64 (matches reference rounding; verified R1-R3)
__device__ __forceinline__ float exp_cr(float x) {
    return (float)::exp((double)x);
}

__global__ void k_zero(unsigned* hist, unsigned* ctr, unsigned* sorted32) {
    int t = blockIdx.x * blockDim.x + threadIdx.x;
    if (t < NBINS) hist[t] = 0u;
    if (t < 16) ctr[t] = 0u;
    if (t < KTOP * 2) sorted32[t] = 0u;   // tail determinism if <KTOP selected
}

// One 32-channel phase of the per-pixel head GEMV. 4 px/thread via float4.
// Continues the sequential fmaf chain from stored partials -> bit-exact vs monolithic.
__global__ __launch_bounds__(256) void k_phase(const float* __restrict__ f,
                       const float* __restrict__ cw, const float* __restrict__ sw,
                       float* __restrict__ pa0, float* __restrict__ pa1,
                       float* __restrict__ pa2, float* __restrict__ pa3,
                       int c0, int first) {
    __shared__ float w0[32], w1[32], w2[32], w3[32];
    int t = threadIdx.x;
    if (t < 32) {
        w0[t] = cw[2*(c0+t)];  w1[t] = cw[2*(c0+t)+1];
        w2[t] = sw[2*(c0+t)];  w3[t] = sw[2*(c0+t)+1];
    }
    __syncthreads();
    int p0 = (blockIdx.x * 256 + t) * 4;
    if (p0 >= HWN) return;
    const long step = HWN / 4;
    const float4* fp = (const float4*)(f + p0) + (long)c0 * step;

    float a0[4], a1[4], a2[4], a3[4];
    if (first) {
        #pragma unroll
        for (int j = 0; j < 4; ++j) { a0[j]=0.f; a1[j]=0.f; a2[j]=0.f; a3[j]=0.f; }
    } else {
        float4 t0 = *(const float4*)(pa0 + p0);
        float4 t1 = *(const float4*)(pa1 + p0);
        float4 t2 = *(const float4*)(pa2 + p0);
        float4 t3 = *(const float4*)(pa3 + p0);
        a0[0]=t0.x; a0[1]=t0.y; a0[2]=t0.z; a0[3]=t0.w;
        a1[0]=t1.x; a1[1]=t1.y; a1[2]=t1.z; a1[3]=t1.w;
        a2[0]=t2.x; a2[1]=t2.y; a2[2]=t2.z; a2[3]=t2.w;
        a3[0]=t3.x; a3[1]=t3.y; a3[2]=t3.z; a3[3]=t3.w;
    }

    float4 A[4], B[4];
    #pragma unroll
    for (int k = 0; k < 4; ++k) A[k] = fp[(long)k * step];

    #define FMA4(REG, CBASE)                                             \
        _Pragma("unroll")                                                \
        for (int k = 0; k < 4; ++k) {                                    \
            int c = (CBASE) + k;                                         \
            float W0 = w0[c], W1 = w1[c], W2 = w2[c], W3 = w3[c];        \
            float vv[4] = {REG[k].x, REG[k].y, REG[k].z, REG[k].w};      \
            _Pragma("unroll")                                            \
            for (int j = 0; j < 4; ++j) {                                \
                float f2 = vv[j] * vv[j];                                \
                a0[j] = fmaf(f2, W0, a0[j]);                             \
                a1[j] = fmaf(f2, W1, a1[j]);                             \
                a2[j] = fmaf(f2, W2, a2[j]);                             \
                a3[j] = fmaf(f2, W3, a3[j]);                             \
            }                                                            \
        }

    for (int cc = 0; cc < 32; cc += 8) {
        #pragma unroll
        for (int k = 0; k < 4; ++k) B[k] = fp[(long)(cc + 4 + k) * step];
        FMA4(A, cc)
        if (cc + 8 < 32) {
            #pragma unroll
            for (int k = 0; k < 4; ++k) A[k] = fp[(long)(cc + 8 + k) * step];
        }
        FMA4(B, cc + 4)
    }
    #undef FMA4

    *(float4*)(pa0 + p0) = make_float4(a0[0], a0[1], a0[2], a0[3]);
    *(float4*)(pa1 + p0) = make_float4(a1[0], a1[1], a1[2], a1[3]);
    *(float4*)(pa2 + p0) = make_float4(a2[0], a2[1], a2[2], a2[3]);
    *(float4*)(pa3 + p0) = make_float4(a3[0], a3[1], a3[2], a3[3]);
}

// epilogue: bias + 2-way softmax (f64 exp), write rep & rel-gated score map
__global__ __launch_bounds__(256) void k_soft(const float* __restrict__ pa0,
                       const float* __restrict__ pa1, const float* __restrict__ pa2,
                       const float* __restrict__ pa3,
                       const float* __restrict__ cb, const float* __restrict__ sb,
                       float* __restrict__ rep, float* __restrict__ smap) {
    int p0 = (blockIdx.x * 256 + threadIdx.x) * 4;
    if (p0 >= HWN) return;
    float4 t0 = *(const float4*)(pa0 + p0);
    float4 t1 = *(const float4*)(pa1 + p0);
    float4 t2 = *(const float4*)(pa2 + p0);
    float4 t3 = *(const float4*)(pa3 + p0);
    float a0[4] = {t0.x,t0.y,t0.z,t0.w}, a1[4] = {t1.x,t1.y,t1.z,t1.w};
    float a2[4] = {t2.x,t2.y,t2.z,t2.w}, a3[4] = {t3.x,t3.y,t3.z,t3.w};
    float cb0 = cb[0], cb1 = cb[1], sb0 = sb[0], sb1 = sb[1];
    float rp4[4], sm4[4];
    #pragma unroll
    for (int j = 0; j < 4; ++j) {
        float u0 = a0[j] + cb0, u1 = a1[j] + cb1;
        float v0 = a2[j] + sb0, v1 = a3[j] + sb1;
        float mr  = fmaxf(u0, u1);
        float er0 = exp_cr(u0 - mr);
        float er1 = exp_cr(u1 - mr);
        float rel = er1 / (er0 + er1);
        float mp  = fmaxf(v0, v1);
        float ep0 = exp_cr(v0 - mp);
        float ep1 = exp_cr(v1 - mp);
        float rp  = ep1 / (ep0 + ep1);
        rp4[j] = rp;
        sm4[j] = (rel >= 0.7f) ? rel * rp : -1.0f;
    }
    *(float4*)(rep + p0)  = make_float4(rp4[0], rp4[1], rp4[2], rp4[3]);
    *(float4*)(smap + p0) = make_float4(sm4[0], sm4[1], sm4[2], sm4[3]);
}

// NMS + fused histogram: center >= all 8 neighbors, rep>=0.7, rel>=0.7
__global__ void k_nms(const float* __restrict__ rep, const float* __restrict__ smap,
                      unsigned long long* __restrict__ cand, unsigned* __restrict__ ctr,
                      unsigned* __restrict__ hist) {
    int p = blockIdx.x * blockDim.x + threadIdx.x;
    if (p >= HWN) return;
    float r = rep[p];
    if (!(r >= 0.7f)) return;
    float s = smap[p];
    if (!(s >= 0.f)) return;
    int x = p & (WW - 1), y = p >> 10;
    float m = -INFINITY;
    if (y > 0) {
        const float* rr = rep + p - WW;
        if (x > 0)      m = fmaxf(m, rr[-1]);
        m = fmaxf(m, rr[0]);
        if (x < WW - 1) m = fmaxf(m, rr[1]);
    }
    if (x > 0)      m = fmaxf(m, rep[p - 1]);
    if (x < WW - 1) m = fmaxf(m, rep[p + 1]);
    if (y < HH - 1) {
        const float* rr = rep + p + WW;
        if (x > 0)      m = fmaxf(m, rr[-1]);
        m = fmaxf(m, rr[0]);
        if (x < WW - 1) m = fmaxf(m, rr[1]);
    }
    if (r < m) return;
    unsigned pos = atomicAdd(&ctr[0], 1u);
    if (pos < CAND_CAP) {
        unsigned sb = __float_as_uint(s);
        cand[pos] = ((unsigned long long)sb << 32) |
                    (unsigned long long)(0xFFFFFFFFu - (unsigned)p);
        int bin = (int)(sb >> 12) - (int)BIN_BASE;
        bin = bin < 0 ? 0 : (bin > NBINS - 1 ? NBINS - 1 : bin);
        atomicAdd(&hist[bin], 1u);
    }
}

// parallel threshold-bin search: suffix-scan of 4096 bins with 1024 threads
__global__ __launch_bounds__(1024) void k_thr(const unsigned* __restrict__ hist,
                                              unsigned* __restrict__ ctr) {
    __shared__ unsigned ps[1024];
    __shared__ int best;
    int t = threadIdx.x;
    if (t == 0) best = -1;
    unsigned h[4];
    unsigned s = 0;
    #pragma unroll
    for (int k = 0; k < 4; ++k) { h[k] = hist[t*4 + k]; s += h[k]; }
    ps[t] = s;
    __syncthreads();
    for (int off = 1; off < 1024; off <<= 1) {
        unsigned v = (t + off < 1024) ? ps[t + off] : 0u;
        __syncthreads();
        ps[t] += v;
        __syncthreads();
    }
    unsigned above4 = (t < 1023) ? ps[t + 1] : 0u;
    int local = -1;
    unsigned cum = above4;
    #pragma unroll
    for (int k = 3; k >= 0; --k) {
        cum += h[k];
        if (local < 0 && cum >= KTOP) local = t*4 + k;
    }
    if (local >= 0) atomicMax(&best, local);
    __syncthreads();
    if (t == 0) {
        int b = best;
        ctr[2] = (b <= 0) ? 0u : ((unsigned)(b + (int)BIN_BASE) << 12);
    }
}

__global__ void k_select(const unsigned long long* __restrict__ cand,
                         unsigned* __restrict__ ctr, unsigned long long* __restrict__ sel) {
    unsigned n = ctr[0]; if (n > CAND_CAP) n = CAND_CAP;
    unsigned thr = ctr[2];
    int stride = gridDim.x * blockDim.x;
    for (unsigned i = blockIdx.x * blockDim.x + threadIdx.x; i < n; i += stride) {
        unsigned long long k = cand[i];
        if ((unsigned)(k >> 32) >= thr) {
            unsigned pos = atomicAdd(&ctr[1], 1u);
            if (pos < SEL_CAP) sel[pos] = k;
        }
    }
}

// exact-rank placement: keys unique -> rank = #{keys > mine}; one wave per 8 entries
__global__ __launch_bounds__(256) void k_rank(const unsigned long long* __restrict__ sel,
                                              const unsigned* __restrict__ ctr,
                                              unsigned long long* __restrict__ sorted) {
    unsigned n = ctr[1]; if (n > SEL_CAP) n = SEL_CAP;
    int wave = (blockIdx.x * 256 + threadIdx.x) >> 6;
    int lane = threadIdx.x & 63;
    int base = wave * 8;
    if (base >= (int)n) return;
    unsigned long long my[8];
    unsigned cnt[8] = {0,0,0,0,0,0,0,0};
    #pragma unroll
    for (int e = 0; e < 8; ++e)
        my[e] = (base + e < (int)n) ? sel[base + e] : ~0ull;
    for (int j = lane; j < (int)n; j += 64) {
        unsigned long long k = sel[j];
        #pragma unroll
        for (int e = 0; e < 8; ++e) cnt[e] += (k > my[e]) ? 1u : 0u;
    }
    #pragma unroll
    for (int e = 0; e < 8; ++e) {
        unsigned c = cnt[e];
        for (int o = 32; o > 0; o >>= 1) c += __shfl_xor(c, o);
        if (lane == 0 && base + e < (int)n && c < KTOP) sorted[c] = my[e];
    }
}

// 2 keypoints per 256-thread block: emit kp/score + gather 128 channels, L2-normalize
__global__ __launch_bounds__(256) void k_desc(const float* __restrict__ f,
                       const unsigned long long* __restrict__ sorted, float* __restrict__ out) {
    __shared__ float partial[4];
    int half = threadIdx.x >> 7;            // 0 or 1
    int r = blockIdx.x * 2 + half;
    int c = threadIdx.x & 127;
    if (r >= KTOP) return;
    unsigned long long key = sorted[r];
    unsigned sbits = (unsigned)(key >> 32);
    unsigned p = 0xFFFFFFFFu - (unsigned)(key & 0xFFFFFFFFull);
    if (p >= HWN) p = 0;
    if (c == 0) {
        int x = p & (WW - 1), y = p >> 10;
        out[2*r]        = (float)x;
        out[2*r + 1]    = (float)y;
        out[2*KTOP + r] = __uint_as_float(sbits);
    }
    float v = f[(long)c * HWN + p];
    float ss = v * v;
    for (int o = 32; o > 0; o >>= 1) ss += __shfl_down(ss, o);
    int w = threadIdx.x >> 6;               // wave id 0..3
    if ((threadIdx.x & 63) == 0) partial[w] = ss;
    __syncthreads();
    float tot = partial[half*2] + partial[half*2 + 1];
    float nm = fmaxf(sqrtf(tot), 1e-12f);
    out[3*KTOP + (long)r*CC + c] = v / nm;
}

extern "C" void kernel_launch(void* const* d_in, const int* in_sizes, int n_in,
                              void* d_out, int out_size, void* d_ws, size_t ws_size,
                              hipStream_t stream) {
    const float* feat = (const float*)d_in[0];
    const float* cw   = (const float*)d_in[1];
    const float* cb   = (const float*)d_in[2];
    const float* sw   = (const float*)d_in[3];
    const float* sb   = (const float*)d_in[4];
    float* out = (float*)d_out;

    char* ws = (char*)d_ws;
    float* rep  = (float*)(ws + OFF_REP);
    float* smap = (float*)(ws + OFF_SMAP);
    unsigned long long* cand   = (unsigned long long*)(ws + OFF_CAND);
    unsigned* hist             = (unsigned*)(ws + OFF_HIST);
    unsigned* ctr              = (unsigned*)(ws + OFF_CTR);
    unsigned long long* sel    = (unsigned long long*)(ws + OFF_SEL);
    unsigned long long* sorted = (unsigned long long*)(ws + OFF_SORTED);
    float* pa0 = (float*)(ws + OFF_PART);
    float* pa1 = (float*)(ws + OFF_PART + 1*PART_PLANE);
    float* pa2 = (float*)(ws + OFF_PART + 2*PART_PLANE);
    float* pa3 = (float*)(ws + OFF_PART + 3*PART_PLANE);

    k_zero<<<dim3(64), dim3(256), 0, stream>>>(hist, ctr, (unsigned*)sorted);
    for (int ph = 0; ph < 4; ++ph) {
        k_phase<<<dim3(HWN / 1024), dim3(256), 0, stream>>>(
            feat, cw, sw, pa0, pa1, pa2, pa3, ph * 32, ph == 0 ? 1 : 0);
    }
    k_soft<<<dim3(HWN / 1024), dim3(256), 0, stream>>>(pa0, pa1, pa2, pa3, cb, sb, rep, smap);
    k_nms<<<dim3(HWN / 256), dim3(256), 0, stream>>>(rep, smap, cand, ctr, hist);
    k_thr<<<dim3(1), dim3(1024), 0, stream>>>(hist, ctr);
    k_select<<<dim3(512), dim3(256), 0, stream>>>(cand, ctr, sel);
    k_rank<<<dim3(256), dim3(256), 0, stream>>>(sel, ctr, sorted);
    k_desc<<<dim3((KTOP + 1) / 2), dim3(256), 0, stream>>>(feat, sorted, out);
}

// Round 5
// 289.214 us; speedup vs baseline: 1.0911x; 1.0911x over previous
//
#include <hip/hip_runtime.h>
#include <math.h>

#define HH   768
#define WW   1024
#define CC   128
#define HWN  (HH*WW)          // 786432
#define KTOP 5000
#define CAND_CAP 204800
#define SEL_CAP  8192
#define NBINS    4096
#define BIN_BASE 0x3E800u     // __float_as_uint(0.25f) >> 12
#define DESC_KP  64

// ---- workspace layout (bytes) ----
#define OFF_REP    0ull
#define OFF_SMAP   3145728ull
#define OFF_CAND   6291456ull
#define OFF_HIST   (OFF_CAND + (unsigned long long)CAND_CAP*8ull)
#define OFF_CTR    (OFF_HIST + (unsigned long long)NBINS*4ull)
#define OFF_SEL    (OFF_CTR + 64ull)
#define OFF_SORTED (OFF_SEL + (unsigned long long)SEL_CAP*8ull)

// correctly-rounded f32 exp via f64 (matches reference rounding; verified R1-R4)
__device__ __forceinline__ float exp_cr(float x) {
    return (float)::exp((double)x);
}

// per-pixel heads, 4 px/thread via float4, software-pipelined channel loads.
// Block 0 additionally zeroes hist/ctr/sorted (consumers run in later kernels).
// FMA accumulation order per pixel is EXACTLY c=0..127 sequential (bit-exact R1-R4).
__global__ __launch_bounds__(256, 4) void k_maps(const float* __restrict__ f,
                       const float* __restrict__ cw, const float* __restrict__ cb,
                       const float* __restrict__ sw, const float* __restrict__ sb,
                       float* __restrict__ rep, float* __restrict__ smap,
                       unsigned* __restrict__ hist, unsigned* __restrict__ ctr,
                       unsigned* __restrict__ sorted32) {
    __shared__ float w0[CC], w1[CC], w2[CC], w3[CC];
    int t = threadIdx.x;
    if (blockIdx.x == 0) {
        for (int i = t; i < NBINS; i += 256) hist[i] = 0u;
        if (t < 16) ctr[t] = 0u;
        for (int i = t; i < KTOP * 2; i += 256) sorted32[i] = 0u;
    }
    if (t < CC) {
        w0[t] = cw[2*t];  w1[t] = cw[2*t+1];
        w2[t] = sw[2*t];  w3[t] = sw[2*t+1];
    }
    __syncthreads();
    int p0 = (blockIdx.x * 256 + t) * 4;
    if (p0 >= HWN) return;
    const float4* fp = (const float4*)(f + p0);
    const long step = HWN / 4;

    float a0[4] = {0,0,0,0}, a1[4] = {0,0,0,0}, a2[4] = {0,0,0,0}, a3[4] = {0,0,0,0};
    float4 A[4], B[4];
    #pragma unroll
    for (int k = 0; k < 4; ++k) A[k] = fp[(long)k * step];

    #define FMA4(REG, CBASE)                                             \
        _Pragma("unroll")                                                \
        for (int k = 0; k < 4; ++k) {                                    \
            int c = (CBASE) + k;                                         \
            float W0 = w0[c], W1 = w1[c], W2 = w2[c], W3 = w3[c];        \
            float vv[4] = {REG[k].x, REG[k].y, REG[k].z, REG[k].w};      \
            _Pragma("unroll")                                            \
            for (int j = 0; j < 4; ++j) {                                \
                float f2 = vv[j] * vv[j];                                \
                a0[j] = fmaf(f2, W0, a0[j]);                             \
                a1[j] = fmaf(f2, W1, a1[j]);                             \
                a2[j] = fmaf(f2, W2, a2[j]);                             \
                a3[j] = fmaf(f2, W3, a3[j]);                             \
            }                                                            \
        }

    for (int c0 = 0; c0 < CC; c0 += 8) {
        #pragma unroll
        for (int k = 0; k < 4; ++k) B[k] = fp[(long)(c0 + 4 + k) * step];
        FMA4(A, c0)
        if (c0 + 8 < CC) {
            #pragma unroll
            for (int k = 0; k < 4; ++k) A[k] = fp[(long)(c0 + 8 + k) * step];
        }
        FMA4(B, c0 + 4)
    }
    #undef FMA4

    float cb0 = cb[0], cb1 = cb[1], sb0 = sb[0], sb1 = sb[1];
    float rp4[4], sm4[4];
    #pragma unroll
    for (int j = 0; j < 4; ++j) {
        float u0 = a0[j] + cb0, u1 = a1[j] + cb1;
        float v0 = a2[j] + sb0, v1 = a3[j] + sb1;
        float mr  = fmaxf(u0, u1);
        float er0 = exp_cr(u0 - mr);
        float er1 = exp_cr(u1 - mr);
        float rel = er1 / (er0 + er1);
        float mp  = fmaxf(v0, v1);
        float ep0 = exp_cr(v0 - mp);
        float ep1 = exp_cr(v1 - mp);
        float rp  = ep1 / (ep0 + ep1);
        rp4[j] = rp;
        sm4[j] = (rel >= 0.7f) ? rel * rp : -1.0f;
    }
    *(float4*)(rep + p0)  = make_float4(rp4[0], rp4[1], rp4[2], rp4[3]);
    *(float4*)(smap + p0) = make_float4(sm4[0], sm4[1], sm4[2], sm4[3]);
}

// NMS + fused histogram: center >= all 8 neighbors, rep>=0.7, rel>=0.7
__global__ void k_nms(const float* __restrict__ rep, const float* __restrict__ smap,
                      unsigned long long* __restrict__ cand, unsigned* __restrict__ ctr,
                      unsigned* __restrict__ hist) {
    int p = blockIdx.x * blockDim.x + threadIdx.x;
    if (p >= HWN) return;
    float r = rep[p];
    if (!(r >= 0.7f)) return;
    float s = smap[p];
    if (!(s >= 0.f)) return;
    int x = p & (WW - 1), y = p >> 10;
    float m = -INFINITY;
    if (y > 0) {
        const float* rr = rep + p - WW;
        if (x > 0)      m = fmaxf(m, rr[-1]);
        m = fmaxf(m, rr[0]);
        if (x < WW - 1) m = fmaxf(m, rr[1]);
    }
    if (x > 0)      m = fmaxf(m, rep[p - 1]);
    if (x < WW - 1) m = fmaxf(m, rep[p + 1]);
    if (y < HH - 1) {
        const float* rr = rep + p + WW;
        if (x > 0)      m = fmaxf(m, rr[-1]);
        m = fmaxf(m, rr[0]);
        if (x < WW - 1) m = fmaxf(m, rr[1]);
    }
    if (r < m) return;
    unsigned pos = atomicAdd(&ctr[0], 1u);
    if (pos < CAND_CAP) {
        unsigned sb = __float_as_uint(s);
        cand[pos] = ((unsigned long long)sb << 32) |
                    (unsigned long long)(0xFFFFFFFFu - (unsigned)p);
        int bin = (int)(sb >> 12) - (int)BIN_BASE;
        bin = bin < 0 ? 0 : (bin > NBINS - 1 ? NBINS - 1 : bin);
        atomicAdd(&hist[bin], 1u);
    }
}

// parallel threshold-bin search: suffix-scan of 4096 bins with 1024 threads
__global__ __launch_bounds__(1024) void k_thr(const unsigned* __restrict__ hist,
                                              unsigned* __restrict__ ctr) {
    __shared__ unsigned ps[1024];
    __shared__ int best;
    int t = threadIdx.x;
    if (t == 0) best = -1;
    unsigned h[4];
    unsigned s = 0;
    #pragma unroll
    for (int k = 0; k < 4; ++k) { h[k] = hist[t*4 + k]; s += h[k]; }
    ps[t] = s;
    __syncthreads();
    for (int off = 1; off < 1024; off <<= 1) {
        unsigned v = (t + off < 1024) ? ps[t + off] : 0u;
        __syncthreads();
        ps[t] += v;
        __syncthreads();
    }
    unsigned above4 = (t < 1023) ? ps[t + 1] : 0u;
    int local = -1;
    unsigned cum = above4;
    #pragma unroll
    for (int k = 3; k >= 0; --k) {
        cum += h[k];
        if (local < 0 && cum >= KTOP) local = t*4 + k;
    }
    if (local >= 0) atomicMax(&best, local);
    __syncthreads();
    if (t == 0) {
        int b = best;
        ctr[2] = (b <= 0) ? 0u : ((unsigned)(b + (int)BIN_BASE) << 12);
    }
}

__global__ void k_select(const unsigned long long* __restrict__ cand,
                         unsigned* __restrict__ ctr, unsigned long long* __restrict__ sel) {
    unsigned n = ctr[0]; if (n > CAND_CAP) n = CAND_CAP;
    unsigned thr = ctr[2];
    int stride = gridDim.x * blockDim.x;
    for (unsigned i = blockIdx.x * blockDim.x + threadIdx.x; i < n; i += stride) {
        unsigned long long k = cand[i];
        if ((unsigned)(k >> 32) >= thr) {
            unsigned pos = atomicAdd(&ctr[1], 1u);
            if (pos < SEL_CAP) sel[pos] = k;
        }
    }
}

// exact-rank placement: keys unique -> rank = #{keys > mine}; one wave per 8 entries
__global__ __launch_bounds__(256) void k_rank(const unsigned long long* __restrict__ sel,
                                              const unsigned* __restrict__ ctr,
                                              unsigned long long* __restrict__ sorted) {
    unsigned n = ctr[1]; if (n > SEL_CAP) n = SEL_CAP;
    int wave = (blockIdx.x * 256 + threadIdx.x) >> 6;
    int lane = threadIdx.x & 63;
    int base = wave * 8;
    if (base >= (int)n) return;
    unsigned long long my[8];
    unsigned cnt[8] = {0,0,0,0,0,0,0,0};
    #pragma unroll
    for (int e = 0; e < 8; ++e)
        my[e] = (base + e < (int)n) ? sel[base + e] : ~0ull;
    for (int j = lane; j < (int)n; j += 64) {
        unsigned long long k = sel[j];
        #pragma unroll
        for (int e = 0; e < 8; ++e) cnt[e] += (k > my[e]) ? 1u : 0u;
    }
    #pragma unroll
    for (int e = 0; e < 8; ++e) {
        unsigned c = cnt[e];
        for (int o = 32; o > 0; o >>= 1) c += __shfl_xor(c, o);
        if (lane == 0 && base + e < (int)n && c < KTOP) sorted[c] = my[e];
    }
}

// 64 keypoints per 256-thread block. lane = keypoint, wave = channel quartile.
// Gathers hit ONE plane per wave-instruction (64 pixels), 32 independent loads/lane.
// Values staged in padded LDS; write-out fully coalesced. Emits kp/score too.
__global__ __launch_bounds__(256) void k_desc(const float* __restrict__ f,
                       const unsigned long long* __restrict__ sorted,
                       float* __restrict__ out) {
    __shared__ float vbuf[DESC_KP][CC + 1];   // +1 pad: conflict-free column writes
    __shared__ float psum[4][DESC_KP];
    __shared__ float nrm[DESC_KP];
    __shared__ unsigned pix[DESC_KP];
    int t = threadIdx.x, w = t >> 6, lane = t & 63;
    int rbase = blockIdx.x * DESC_KP;

    if (t < DESC_KP) {
        int r = rbase + t;
        unsigned long long key = (r < KTOP) ? sorted[r] : 0ull;
        unsigned sbits = (unsigned)(key >> 32);
        unsigned p = 0xFFFFFFFFu - (unsigned)(key & 0xFFFFFFFFull);
        if (p >= HWN) p = 0;
        pix[t] = p;
        if (r < KTOP) {
            out[2*r]        = (float)(p & (WW - 1));
            out[2*r + 1]    = (float)(p >> 10);
            out[2*KTOP + r] = __uint_as_float(sbits);
        }
    }
    __syncthreads();
    unsigned p = pix[lane];
    float ss = 0.f;
    #pragma unroll 8
    for (int cc = 0; cc < 32; ++cc) {
        int c = w * 32 + cc;
        float v = f[(long)c * HWN + p];
        vbuf[lane][c] = v;
        ss = fmaf(v, v, ss);
    }
    psum[w][lane] = ss;
    __syncthreads();
    if (t < DESC_KP) {
        float tot = psum[0][t] + psum[1][t] + psum[2][t] + psum[3][t];
        nrm[t] = fmaxf(sqrtf(tot), 1e-12f);
    }
    __syncthreads();
    int kp2 = t >> 7;          // 0 or 1
    int c   = t & 127;
    for (int it = 0; it < DESC_KP / 2; ++it) {
        int kp = it * 2 + kp2;
        int r  = rbase + kp;
        if (r < KTOP)
            out[3*KTOP + (long)r*CC + c] = vbuf[kp][c] / nrm[kp];
    }
}

extern "C" void kernel_launch(void* const* d_in, const int* in_sizes, int n_in,
                              void* d_out, int out_size, void* d_ws, size_t ws_size,
                              hipStream_t stream) {
    const float* feat = (const float*)d_in[0];
    const float* cw   = (const float*)d_in[1];
    const float* cb   = (const float*)d_in[2];
    const float* sw   = (const float*)d_in[3];
    const float* sb   = (const float*)d_in[4];
    float* out = (float*)d_out;

    char* ws = (char*)d_ws;
    float* rep  = (float*)(ws + OFF_REP);
    float* smap = (float*)(ws + OFF_SMAP);
    unsigned long long* cand   = (unsigned long long*)(ws + OFF_CAND);
    unsigned* hist             = (unsigned*)(ws + OFF_HIST);
    unsigned* ctr              = (unsigned*)(ws + OFF_CTR);
    unsigned long long* sel    = (unsigned long long*)(ws + OFF_SEL);
    unsigned long long* sorted = (unsigned long long*)(ws + OFF_SORTED);

    k_maps<<<dim3(HWN / 1024), dim3(256), 0, stream>>>(feat, cw, cb, sw, sb, rep, smap,
                                                       hist, ctr, (unsigned*)sorted);
    k_nms<<<dim3(HWN / 256), dim3(256), 0, stream>>>(rep, smap, cand, ctr, hist);
    k_thr<<<dim3(1), dim3(1024), 0, stream>>>(hist, ctr);
    k_select<<<dim3(512), dim3(256), 0, stream>>>(cand, ctr, sel);
    k_rank<<<dim3(256), dim3(256), 0, stream>>>(sel, ctr, sorted);
    k_desc<<<dim3((KTOP + DESC_KP - 1) / DESC_KP), dim3(256), 0, stream>>>(feat, sorted, out);
}